// Round 1
// baseline (253.788 us; speedup 1.0000x reference)
//
#include <hip/hip_runtime.h>
#include <hip/hip_bf16.h>

#define D_BLADE 256
#define D_FFN 1024
#define N_TOK 8192
#define M_TOTAL (N_TOK * 8)

#define BM 64
#define SNP 264   // padded LDS row for normed tile (stride 528B -> uniform 8-way 16B slots)
#define SHP 136   // padded LDS row for h chunk  (stride 272B -> same)
#define FC 128    // F processed per chunk

typedef __attribute__((ext_vector_type(8))) short bf16x8;
typedef __attribute__((ext_vector_type(4))) float f32x4;

__device__ __forceinline__ float sigm(float v) { return 1.0f / (1.0f + __expf(-v)); }

// ---------------- weights fp32 -> bf16 ----------------
__global__ __launch_bounds__(256) void wconv_kernel(const float* __restrict__ g,
                                                    const float* __restrict__ u,
                                                    const float* __restrict__ dn,
                                                    __hip_bfloat16* __restrict__ gb,
                                                    __hip_bfloat16* __restrict__ ub,
                                                    __hip_bfloat16* __restrict__ db) {
    int i = blockIdx.x * 256 + threadIdx.x;   // grid covers 1024*256 = 262144 = D_FFN*D_BLADE
    gb[i] = __float2bfloat16(g[i]);
    ub[i] = __float2bfloat16(u[i]);
    db[i] = __float2bfloat16(dn[i]);
}

// ---------------- geometric product + mix + LayerNorm -> normed (bf16) ----------------
__global__ __launch_bounds__(256) void geo_ln_kernel(
    const float* __restrict__ x, const float* __restrict__ iw,
    const float* __restrict__ sg, const float* __restrict__ gg,
    const float* __restrict__ lnw, const float* __restrict__ lnb,
    __hip_bfloat16* __restrict__ nrm)
{
    // Cayley target-index table for Cl(3,0), basis [1,e1,e2,e3,e12,e13,e23,e123].
    // p = i*8 + j -> k; signs come from the sg input (multiplied into coefs).
    static constexpr int CK[64] = {
        0,1,2,3,4,5,6,7,
        1,0,4,5,2,3,7,6,
        2,4,0,6,1,7,3,5,
        3,5,6,0,7,1,2,4,
        4,2,1,7,0,6,5,3,
        5,3,7,1,6,0,4,2,
        6,7,3,2,5,4,0,1,
        7,6,5,4,3,2,1,0};
    __shared__ float coefs[64];
    __shared__ float redA[4][8];
    __shared__ float redB[4][8];
    const int tid = threadIdx.x;          // = d index, 0..255
    const int n = blockIdx.x;             // token
    if (tid < 64) coefs[tid] = sg[tid] * sigm(iw[tid]);
    __syncthreads();

    const float* xp = x + (size_t)n * (8 * D_BLADE) + tid;
    float xa[8];
#pragma unroll
    for (int b = 0; b < 8; ++b) xa[b] = xp[b * D_BLADE];

    float geo[8] = {0.f,0.f,0.f,0.f,0.f,0.f,0.f,0.f};
#pragma unroll
    for (int p = 0; p < 64; ++p)
        geo[CK[p]] += coefs[p] * xa[p >> 3] * xa[p & 7];

    const float g = sigm(gg[0]);
    float mixed[8], sm[8], sq[8];
#pragma unroll
    for (int b = 0; b < 8; ++b) {
        mixed[b] = g * geo[b] + (1.0f - g) * xa[b];
        sm[b] = mixed[b];
        sq[b] = mixed[b] * mixed[b];
    }
    // wave64 butterfly reduce (8 blades x {sum, sumsq})
#pragma unroll
    for (int off = 32; off > 0; off >>= 1) {
#pragma unroll
        for (int b = 0; b < 8; ++b) {
            sm[b] += __shfl_xor(sm[b], off, 64);
            sq[b] += __shfl_xor(sq[b], off, 64);
        }
    }
    const int wv = tid >> 6;
    if ((tid & 63) == 0) {
#pragma unroll
        for (int b = 0; b < 8; ++b) { redA[wv][b] = sm[b]; redB[wv][b] = sq[b]; }
    }
    __syncthreads();

    const float lw = lnw[tid], lb = lnb[tid];
    __hip_bfloat16* op = nrm + ((size_t)n * 8) * D_BLADE + tid;
#pragma unroll
    for (int b = 0; b < 8; ++b) {
        float ts = redA[0][b] + redA[1][b] + redA[2][b] + redA[3][b];
        float tq = redB[0][b] + redB[1][b] + redB[2][b] + redB[3][b];
        float mu = ts * (1.0f / 256.0f);
        float var = tq * (1.0f / 256.0f) - mu * mu;
        float rs = rsqrtf(var + 1e-5f);
        op[b * D_BLADE] = __float2bfloat16((mixed[b] - mu) * rs * lw + lb);
    }
}

// ---------------- fused SwiGLU FFN + residual ----------------
// Block: 64 rows (BM), 512 threads (8 waves). Per F-chunk of 128:
//   phase2: each wave computes h rows for its 16-F stripe over 4 M-tiles (gate+up)
//   phase3: each wave accumulates down-GEMM partials for its 2 col-tiles x 4 M-tiles
__global__ __launch_bounds__(512) void ffn_kernel(
    const __hip_bfloat16* __restrict__ nrm,
    const __hip_bfloat16* __restrict__ gw,
    const __hip_bfloat16* __restrict__ uw,
    const __hip_bfloat16* __restrict__ dw,
    const float* __restrict__ x,
    float* __restrict__ out)
{
    __shared__ __hip_bfloat16 sN[BM][SNP];
    __shared__ __hip_bfloat16 sH[BM][SHP];
    const int tid = threadIdx.x;
    const int l = tid & 63;
    const int w = tid >> 6;       // wave 0..7
    const int rr = l & 15;        // row-within-16 for A/B frags, col for C/D
    const int kq = l >> 4;        // 0..3 (k-chunk select / C row group)
    const int kr = kq * 8;        // k sub-offset within 32
    const int m0 = blockIdx.x * BM;

    // stage normed tile 64x256 bf16 into LDS
#pragma unroll
    for (int it = 0; it < 4; ++it) {
        int idx = it * 4096 + tid * 8;
        int r = idx >> 8, c = idx & 255;
        bf16x8 v = *reinterpret_cast<const bf16x8*>(nrm + (size_t)(m0 + r) * D_BLADE + c);
        *reinterpret_cast<bf16x8*>(&sN[r][c]) = v;
    }
    __syncthreads();

    const f32x4 zero = {0.f, 0.f, 0.f, 0.f};
    f32x4 acc_o[4][2];
#pragma unroll
    for (int mt = 0; mt < 4; ++mt) { acc_o[mt][0] = zero; acc_o[mt][1] = zero; }

    for (int fc = 0; fc < 8; ++fc) {
        // ---- phase 2: gate/up for this wave's 16-F stripe ----
        f32x4 ag[4], au[4];
#pragma unroll
        for (int mt = 0; mt < 4; ++mt) { ag[mt] = zero; au[mt] = zero; }
        const __hip_bfloat16* gR = gw + (size_t)(fc * FC + w * 16 + rr) * D_BLADE + kr;
        const __hip_bfloat16* uR = uw + (size_t)(fc * FC + w * 16 + rr) * D_BLADE + kr;
#pragma unroll
        for (int kk = 0; kk < 8; ++kk) {
            bf16x8 bg = *reinterpret_cast<const bf16x8*>(gR + kk * 32);
            bf16x8 bu = *reinterpret_cast<const bf16x8*>(uR + kk * 32);
#pragma unroll
            for (int mt = 0; mt < 4; ++mt) {
                bf16x8 a = *reinterpret_cast<const bf16x8*>(&sN[mt * 16 + rr][kk * 32 + kr]);
                ag[mt] = __builtin_amdgcn_mfma_f32_16x16x32_bf16(a, bg, ag[mt], 0, 0, 0);
                au[mt] = __builtin_amdgcn_mfma_f32_16x16x32_bf16(a, bu, au[mt], 0, 0, 0);
            }
        }
        // silu(gate)*up -> sH (previous chunk's phase3 finished at end-of-loop barrier)
#pragma unroll
        for (int mt = 0; mt < 4; ++mt) {
#pragma unroll
            for (int r = 0; r < 4; ++r) {
                float gv = ag[mt][r];
                float uv = au[mt][r];
                float hv = gv * sigm(gv) * uv;
                sH[mt * 16 + kq * 4 + r][w * 16 + rr] = __float2bfloat16(hv);
            }
        }
        __syncthreads();
        // ---- phase 3: down-GEMM partial over this chunk's K=128 ----
        const __hip_bfloat16* dR0 = dw + (size_t)((w * 2 + 0) * 16 + rr) * D_FFN + fc * FC + kr;
        const __hip_bfloat16* dR1 = dw + (size_t)((w * 2 + 1) * 16 + rr) * D_FFN + fc * FC + kr;
#pragma unroll
        for (int kk = 0; kk < 4; ++kk) {
            bf16x8 b0 = *reinterpret_cast<const bf16x8*>(dR0 + kk * 32);
            bf16x8 b1 = *reinterpret_cast<const bf16x8*>(dR1 + kk * 32);
#pragma unroll
            for (int mt = 0; mt < 4; ++mt) {
                bf16x8 a = *reinterpret_cast<const bf16x8*>(&sH[mt * 16 + rr][kk * 32 + kr]);
                acc_o[mt][0] = __builtin_amdgcn_mfma_f32_16x16x32_bf16(a, b0, acc_o[mt][0], 0, 0, 0);
                acc_o[mt][1] = __builtin_amdgcn_mfma_f32_16x16x32_bf16(a, b1, acc_o[mt][1], 0, 0, 0);
            }
        }
        __syncthreads();
    }

    // epilogue: residual add, f32 store
#pragma unroll
    for (int mt = 0; mt < 4; ++mt) {
#pragma unroll
        for (int cs = 0; cs < 2; ++cs) {
#pragma unroll
            for (int r = 0; r < 4; ++r) {
                int m = m0 + mt * 16 + kq * 4 + r;
                int dcol = (w * 2 + cs) * 16 + rr;
                size_t idx = (size_t)m * D_BLADE + dcol;
                out[idx] = x[idx] + acc_o[mt][cs][r];
            }
        }
    }
}

extern "C" void kernel_launch(void* const* d_in, const int* in_sizes, int n_in,
                              void* d_out, int out_size, void* d_ws, size_t ws_size,
                              hipStream_t stream) {
    const float* x   = (const float*)d_in[0];
    const float* iw  = (const float*)d_in[1];
    const float* sg  = (const float*)d_in[2];
    const float* gg  = (const float*)d_in[3];
    const float* gwf = (const float*)d_in[4];
    const float* uwf = (const float*)d_in[5];
    const float* dwf = (const float*)d_in[6];
    const float* lnw = (const float*)d_in[7];
    const float* lnb = (const float*)d_in[8];
    float* out = (float*)d_out;

    char* ws = (char*)d_ws;
    __hip_bfloat16* nrm = (__hip_bfloat16*)ws;                                   // 33.5 MB
    __hip_bfloat16* gb  = (__hip_bfloat16*)(ws + (size_t)M_TOTAL * D_BLADE * 2); // 512 KB
    __hip_bfloat16* ub  = gb + (size_t)D_FFN * D_BLADE;
    __hip_bfloat16* db  = ub + (size_t)D_FFN * D_BLADE;

    wconv_kernel<<<dim3((D_FFN * D_BLADE) / 256), dim3(256), 0, stream>>>(gwf, uwf, dwf, gb, ub, db);
    geo_ln_kernel<<<dim3(N_TOK), dim3(256), 0, stream>>>(x, iw, sg, gg, lnw, lnb, nrm);
    ffn_kernel<<<dim3(M_TOTAL / BM), dim3(512), 0, stream>>>(nrm, gb, ub, db, x, out);
}